// Round 5
// baseline (390.993 us; speedup 1.0000x reference)
//
#include <hip/hip_runtime.h>
#include <hip/hip_fp16.h>

// Problem constants (fixed by setup_inputs): B=1, KVH=8, D=128, S=8192
#define HH 8
#define DD 128
#define SS 8192

typedef float f32x4 __attribute__((ext_vector_type(4)));

// ---------------- attn mask fill: out[r][c] = (c>r ? -128 : 0) * mask ----------------
// Fill-like structure: 2048 blocks, each thread stores 32 float4 grid-strided.
// Each grid iteration covers a contiguous 8 MB span (2048 blk x 256 thr x 16 B).
// Tests whether the 65536-one-shot-block version was wg-dispatch-rate-bound.
// (Round-3 benched this structure only confounded with NT loads, now known -8 us.)
#define ATTN_BLOCKS 2048
__global__ __launch_bounds__(256) void attn_kernel(const int* __restrict__ maskp,
                                                   float* __restrict__ out) {
    const float hi = (float)(-128 * (*maskp));
    int idx = blockIdx.x * 256 + threadIdx.x;    // float4 index
#pragma unroll
    for (int it = 0; it < 32; ++it, idx += ATTN_BLOCKS * 256) {
        const int r = idx >> 11;                 // row (2048 float4 per row)
        const int c = (idx & 2047) << 2;         // first col of this float4
        f32x4 v;
        v.x = (c + 0 > r) ? hi : 0.0f;
        v.y = (c + 1 > r) ? hi : 0.0f;
        v.z = (c + 2 > r) ? hi : 0.0f;
        v.w = (c + 3 > r) ? hi : 0.0f;
        *((f32x4*)out + idx) = v;
    }
}

// ---------------- keys: layout (H, D, S), quantize over D (stride S) ----------------
// 1024 blocks, one per (h, 64-wide s-tile). 16 B/lane: lane owns a float4 along s.
// sq = s-quad (16 per tile), dg = d-group (16 groups x 8 rows). Plain (cached) loads
// (NT loads measured -8 us total, rounds 3->4). Data cached in 32 VGPRs.
__global__ __launch_bounds__(256) void keys_kernel(const float* __restrict__ keys,
                                                   float* __restrict__ kp,
                                                   float* __restrict__ ks,
                                                   float* __restrict__ kb) {
    const int h  = blockIdx.x >> 7;
    const int s0 = (blockIdx.x & 127) << 6;
    const int sq = threadIdx.x & 15;
    const int dg = threadIdx.x >> 4;

    const float* base = keys + (size_t)h * DD * SS + (size_t)dg * 8 * SS + s0 + sq * 4;
    f32x4 v[8];
    f32x4 mn4, mx4;
    mn4.x = mn4.y = mn4.z = mn4.w = 3.0e38f;
    mx4.x = mx4.y = mx4.z = mx4.w = -3.0e38f;
#pragma unroll
    for (int j = 0; j < 8; ++j) {
        v[j] = *(const f32x4*)(base + (size_t)j * SS);
        mn4.x = fminf(mn4.x, v[j].x); mx4.x = fmaxf(mx4.x, v[j].x);
        mn4.y = fminf(mn4.y, v[j].y); mx4.y = fmaxf(mx4.y, v[j].y);
        mn4.z = fminf(mn4.z, v[j].z); mx4.z = fmaxf(mx4.z, v[j].z);
        mn4.w = fminf(mn4.w, v[j].w); mx4.w = fmaxf(mx4.w, v[j].w);
    }

    __shared__ f32x4 smn[16][16], smx[16][16];
    __shared__ float sinv[64], sbi[64];
    smn[dg][sq] = mn4;
    smx[dg][sq] = mx4;
    __syncthreads();
    if (threadIdx.x < 64) {
        // lane t reduces s-column s0+t over the 16 d-groups. LDS word = gg*64+t:
        // 2 lanes/bank across the wave -> conflict-free (m136).
        const int q = threadIdx.x >> 2, cmp = threadIdx.x & 3;
        float m = 3.0e38f, M = -3.0e38f;
#pragma unroll
        for (int gg = 0; gg < 16; ++gg) {
            m = fminf(m, ((const float*)&smn[gg][q])[cmp]);
            M = fmaxf(M, ((const float*)&smx[gg][q])[cmp]);
        }
        const float scale = (M - m) * (1.0f / 255.0f);  // fp32, matches ref
        sinv[threadIdx.x] = 1.0f / scale;                // reciprocal for packing
        sbi[threadIdx.x]  = m;
        const int o = h * SS + s0 + threadIdx.x;         // k_scale/k_bias flat [h][s]
        ks[o] = __half2float(__float2half(scale));       // astype(f16) round-trip, RNE
        kb[o] = __half2float(__float2half(m));
    }
    __syncthreads();
    const f32x4 rs = *(const f32x4*)&sinv[sq * 4];
    const f32x4 bi = *(const f32x4*)&sbi[sq * 4];
    float* ob = kp + (size_t)h * DD * SS + (size_t)dg * 8 * SS + s0 + sq * 4;
#pragma unroll
    for (int j = 0; j < 8; ++j) {
        f32x4 o;
        o.x = rintf((v[j].x - bi.x) * rs.x);
        o.y = rintf((v[j].y - bi.y) * rs.y);
        o.z = rintf((v[j].z - bi.z) * rs.z);
        o.w = rintf((v[j].w - bi.w) * rs.w);
        *(f32x4*)(ob + (size_t)j * SS) = o;
    }
}

// ---------------- values: layout (H, S, D), quantize over contiguous D=128 ----------------
// Round-0/4 structure: 8192 blocks x 8 rows. 32 lanes per row, one float4 each (512B
// contiguous per 32-lane group). Butterfly __shfl_xor (offsets 1..16) stays within
// each 32-lane group on wave64. Reciprocal-mul kept (verified: absmax 1.0 -> 1.2e-4).
__global__ __launch_bounds__(256) void vals_kernel(const float* __restrict__ vals,
                                                   float* __restrict__ vp,
                                                   float* __restrict__ vs,
                                                   float* __restrict__ vb) {
    const int d4 = threadIdx.x & 31;          // float4 index within row
    const int rr = threadIdx.x >> 5;          // 0..7 rows per block
    const int R  = blockIdx.x * 8 + rr;       // global row: R = h*8192 + s

    const f32x4 v = ((const f32x4*)vals)[R * 32 + d4];
    float mn = fminf(fminf(v.x, v.y), fminf(v.z, v.w));
    float mx = fmaxf(fmaxf(v.x, v.y), fmaxf(v.z, v.w));
#pragma unroll
    for (int off = 16; off >= 1; off >>= 1) {
        mn = fminf(mn, __shfl_xor(mn, off));
        mx = fmaxf(mx, __shfl_xor(mx, off));
    }
    const float scale = (mx - mn) * (1.0f / 255.0f);
    const float inv   = 1.0f / scale;
    if (d4 == 0) {
        // v_scale swapaxes(-1,-2) is a no-op on flat memory: both flat [h][s] = [R]
        vs[R] = __half2float(__float2half(scale));
        vb[R] = __half2float(__float2half(mn));
    }
    f32x4 o;
    o.x = rintf((v.x - mn) * inv);
    o.y = rintf((v.y - mn) * inv);
    o.z = rintf((v.z - mn) * inv);
    o.w = rintf((v.w - mn) * inv);
    ((f32x4*)vp)[R * 32 + d4] = o;
}

extern "C" void kernel_launch(void* const* d_in, const int* in_sizes, int n_in,
                              void* d_out, int out_size, void* d_ws, size_t ws_size,
                              hipStream_t stream) {
    const float* keys  = (const float*)d_in[0];
    const float* vals  = (const float*)d_in[1];
    const int*   maskp = (const int*)d_in[2];
    // d_in[3] = ids_len, d_in[4] = kv_seq_len — fixed at 8192 (they define output shapes)

    float* out  = (float*)d_out;
    float* attn = out;                       // 8192*8192      = 67108864
    float* kp   = attn + 67108864;           // 8*128*8192     =  8388608
    float* ks   = kp   + 8388608;            // 8*8192         =    65536
    float* kb   = ks   + 65536;              //                     65536
    float* vp   = kb   + 65536;              //                   8388608
    float* vs   = vp   + 8388608;            //                     65536
    float* vb   = vs   + 65536;              //                     65536

    attn_kernel<<<dim3(ATTN_BLOCKS), dim3(256), 0, stream>>>(maskp, attn);
    keys_kernel<<<dim3(HH * (SS / 64)), dim3(256), 0, stream>>>(keys, kp, ks, kb);
    vals_kernel<<<dim3(HH * SS / 8), dim3(256), 0, stream>>>(vals, vp, vs, vb);
}

// Round 6
// 374.717 us; speedup vs baseline: 1.0434x; 1.0434x over previous
//
#include <hip/hip_runtime.h>
#include <hip/hip_fp16.h>

// Problem constants (fixed by setup_inputs): B=1, KVH=8, D=128, S=8192
#define HH 8
#define DD 128
#define SS 8192

typedef float f32x4 __attribute__((ext_vector_type(4)));

// Measured-best configuration (R0: 375.3 us, R4: 375.7 us). A/B-tested variants that
// LOST: fused single-dispatch (R1/R2: 383-386), grid-stride attn (R3/R5: 384-391),
// NT loads/stores (neutral-to-negative). Kept improvements vs original session:
// reciprocal-mul quantize (absmax 1.0 -> 1.2e-4) and 16B/lane keys loads.

// ---------------- attn mask fill: out[r][c] = (c>r ? -128 : 0) * mask ----------------
// 8192x8192 fp32, one float4 per thread, 65536 one-shot blocks. Pure store kernel.
// A/B vs 2048-block grid-stride (R5): one-shot is 15 us faster.
__global__ __launch_bounds__(256) void attn_kernel(const int* __restrict__ maskp,
                                                   float* __restrict__ out) {
    const float hi = (float)(-128 * (*maskp));
    int idx = blockIdx.x * 256 + threadIdx.x;   // float4 index, 0 .. 8192*2048-1
    int r  = idx >> 11;                          // row
    int c  = (idx & 2047) << 2;                  // first col of this float4
    f32x4 v;
    v.x = (c + 0 > r) ? hi : 0.0f;
    v.y = (c + 1 > r) ? hi : 0.0f;
    v.z = (c + 2 > r) ? hi : 0.0f;
    v.w = (c + 3 > r) ? hi : 0.0f;
    ((f32x4*)out)[idx] = v;
}

// ---------------- keys: layout (H, D, S), quantize over D (stride S) ----------------
// 1024 blocks, one per (h, 64-wide s-tile). 16 B/lane: lane owns a float4 along s.
// sq = s-quad (16 per tile), dg = d-group (16 groups x 8 rows). Wave reads 4x256B
// segments per instruction; data cached in 32 VGPRs between min/max and pack.
__global__ __launch_bounds__(256) void keys_kernel(const float* __restrict__ keys,
                                                   float* __restrict__ kp,
                                                   float* __restrict__ ks,
                                                   float* __restrict__ kb) {
    const int h  = blockIdx.x >> 7;
    const int s0 = (blockIdx.x & 127) << 6;
    const int sq = threadIdx.x & 15;
    const int dg = threadIdx.x >> 4;

    const float* base = keys + (size_t)h * DD * SS + (size_t)dg * 8 * SS + s0 + sq * 4;
    f32x4 v[8];
    f32x4 mn4, mx4;
    mn4.x = mn4.y = mn4.z = mn4.w = 3.0e38f;
    mx4.x = mx4.y = mx4.z = mx4.w = -3.0e38f;
#pragma unroll
    for (int j = 0; j < 8; ++j) {
        v[j] = *(const f32x4*)(base + (size_t)j * SS);
        mn4.x = fminf(mn4.x, v[j].x); mx4.x = fmaxf(mx4.x, v[j].x);
        mn4.y = fminf(mn4.y, v[j].y); mx4.y = fmaxf(mx4.y, v[j].y);
        mn4.z = fminf(mn4.z, v[j].z); mx4.z = fmaxf(mx4.z, v[j].z);
        mn4.w = fminf(mn4.w, v[j].w); mx4.w = fmaxf(mx4.w, v[j].w);
    }

    __shared__ f32x4 smn[16][16], smx[16][16];
    __shared__ float sinv[64], sbi[64];
    smn[dg][sq] = mn4;
    smx[dg][sq] = mx4;
    __syncthreads();
    if (threadIdx.x < 64) {
        // lane t reduces s-column s0+t over the 16 d-groups. LDS word = gg*64+t:
        // 2 lanes/bank across the wave -> conflict-free (m136).
        const int q = threadIdx.x >> 2, cmp = threadIdx.x & 3;
        float m = 3.0e38f, M = -3.0e38f;
#pragma unroll
        for (int gg = 0; gg < 16; ++gg) {
            m = fminf(m, ((const float*)&smn[gg][q])[cmp]);
            M = fmaxf(M, ((const float*)&smx[gg][q])[cmp]);
        }
        const float scale = (M - m) * (1.0f / 255.0f);  // fp32, matches ref
        sinv[threadIdx.x] = 1.0f / scale;                // reciprocal for packing
        sbi[threadIdx.x]  = m;
        const int o = h * SS + s0 + threadIdx.x;         // k_scale/k_bias flat [h][s]
        ks[o] = __half2float(__float2half(scale));       // astype(f16) round-trip, RNE
        kb[o] = __half2float(__float2half(m));
    }
    __syncthreads();
    const f32x4 rs = *(const f32x4*)&sinv[sq * 4];
    const f32x4 bi = *(const f32x4*)&sbi[sq * 4];
    float* ob = kp + (size_t)h * DD * SS + (size_t)dg * 8 * SS + s0 + sq * 4;
#pragma unroll
    for (int j = 0; j < 8; ++j) {
        f32x4 o;
        o.x = rintf((v[j].x - bi.x) * rs.x);
        o.y = rintf((v[j].y - bi.y) * rs.y);
        o.z = rintf((v[j].z - bi.z) * rs.z);
        o.w = rintf((v[j].w - bi.w) * rs.w);
        *(f32x4*)(ob + (size_t)j * SS) = o;
    }
}

// ---------------- values: layout (H, S, D), quantize over contiguous D=128 ----------------
// 8192 blocks x 8 rows. 32 lanes per row, one float4 each (512B contiguous per
// 32-lane group). Butterfly __shfl_xor (offsets 1..16) stays within each 32-lane
// group on wave64.
__global__ __launch_bounds__(256) void vals_kernel(const float* __restrict__ vals,
                                                   float* __restrict__ vp,
                                                   float* __restrict__ vs,
                                                   float* __restrict__ vb) {
    const int d4 = threadIdx.x & 31;          // float4 index within row
    const int rr = threadIdx.x >> 5;          // 0..7 rows per block
    const int R  = blockIdx.x * 8 + rr;       // global row: R = h*8192 + s

    const f32x4 v = ((const f32x4*)vals)[R * 32 + d4];
    float mn = fminf(fminf(v.x, v.y), fminf(v.z, v.w));
    float mx = fmaxf(fmaxf(v.x, v.y), fmaxf(v.z, v.w));
#pragma unroll
    for (int off = 16; off >= 1; off >>= 1) {
        mn = fminf(mn, __shfl_xor(mn, off));
        mx = fmaxf(mx, __shfl_xor(mx, off));
    }
    const float scale = (mx - mn) * (1.0f / 255.0f);
    const float inv   = 1.0f / scale;
    if (d4 == 0) {
        // v_scale swapaxes(-1,-2) is a no-op on flat memory: both flat [h][s] = [R]
        vs[R] = __half2float(__float2half(scale));
        vb[R] = __half2float(__float2half(mn));
    }
    f32x4 o;
    o.x = rintf((v.x - mn) * inv);
    o.y = rintf((v.y - mn) * inv);
    o.z = rintf((v.z - mn) * inv);
    o.w = rintf((v.w - mn) * inv);
    ((f32x4*)vp)[R * 32 + d4] = o;
}

extern "C" void kernel_launch(void* const* d_in, const int* in_sizes, int n_in,
                              void* d_out, int out_size, void* d_ws, size_t ws_size,
                              hipStream_t stream) {
    const float* keys  = (const float*)d_in[0];
    const float* vals  = (const float*)d_in[1];
    const int*   maskp = (const int*)d_in[2];
    // d_in[3] = ids_len, d_in[4] = kv_seq_len — fixed at 8192 (they define output shapes)

    float* out  = (float*)d_out;
    float* attn = out;                       // 8192*8192      = 67108864
    float* kp   = attn + 67108864;           // 8*128*8192     =  8388608
    float* ks   = kp   + 8388608;            // 8*8192         =    65536
    float* kb   = ks   + 65536;              //                     65536
    float* vp   = kb   + 65536;              //                   8388608
    float* vs   = vp   + 8388608;            //                     65536
    float* vb   = vs   + 65536;              //                     65536

    attn_kernel<<<dim3(SS * (SS / 4) / 256), dim3(256), 0, stream>>>(maskp, attn);
    keys_kernel<<<dim3(HH * (SS / 64)), dim3(256), 0, stream>>>(keys, kp, ks, kb);
    vals_kernel<<<dim3(HH * SS / 8), dim3(256), 0, stream>>>(vals, vp, vs, vb);
}